// Round 6
// baseline (903.008 us; speedup 1.0000x reference)
//
#include <hip/hip_runtime.h>
#include <hip/hip_bf16.h>

#define NEG_SLOPE 0.2f

// ---------------------------------------------------------------------------
// Tiled f32 GEMM: D[V,128] = act(A[V,128] @ W[128,128] + bias), optional lrelu
// ---------------------------------------------------------------------------
__global__ __launch_bounds__(256) void gemm128(const float* __restrict__ A,
                                               const float* __restrict__ W,
                                               const float* __restrict__ bias,
                                               float* __restrict__ D,
                                               int V, int lrelu)
{
    __shared__ float As[32][65];    // transposed [k][row], padded
    __shared__ float Bs[32][128];   // [k][col]
    const int tid = threadIdx.x;
    const int tx = tid & 15;
    const int ty = tid >> 4;
    const int row0 = blockIdx.x * 64;

    float acc[4][8];
#pragma unroll
    for (int i = 0; i < 4; ++i)
#pragma unroll
        for (int j = 0; j < 8; ++j) acc[i][j] = 0.f;

    for (int k0 = 0; k0 < 128; k0 += 32) {
        {
            const int c = (tid & 7) * 4;
#pragma unroll
            for (int p = 0; p < 2; ++p) {
                const int r = (tid >> 3) + 32 * p;
                const int gr = row0 + r;
                float4 a = make_float4(0.f, 0.f, 0.f, 0.f);
                if (gr < V) a = *(const float4*)(A + (size_t)gr * 128 + k0 + c);
                As[c + 0][r] = a.x; As[c + 1][r] = a.y;
                As[c + 2][r] = a.z; As[c + 3][r] = a.w;
            }
        }
        {
            const int r = tid >> 5;
            const int c = (tid & 31) * 4;
#pragma unroll
            for (int p = 0; p < 4; ++p) {
                float4 b = *(const float4*)(W + (size_t)(k0 + r + 8 * p) * 128 + c);
                *(float4*)&Bs[r + 8 * p][c] = b;
            }
        }
        __syncthreads();
#pragma unroll 8
        for (int kk = 0; kk < 32; ++kk) {
            float a[4];
#pragma unroll
            for (int i = 0; i < 4; ++i) a[i] = As[kk][ty * 4 + i];
            const float4 b0 = *(const float4*)&Bs[kk][tx * 8];
            const float4 b1 = *(const float4*)&Bs[kk][tx * 8 + 4];
            const float b[8] = {b0.x, b0.y, b0.z, b0.w, b1.x, b1.y, b1.z, b1.w};
#pragma unroll
            for (int i = 0; i < 4; ++i)
#pragma unroll
                for (int j = 0; j < 8; ++j) acc[i][j] += a[i] * b[j];
        }
        __syncthreads();
    }

#pragma unroll
    for (int i = 0; i < 4; ++i) {
        const int gr = row0 + ty * 4 + i;
        if (gr >= V) continue;
#pragma unroll
        for (int j = 0; j < 8; j += 4) {
            float4 o;
            float* op = &o.x;
#pragma unroll
            for (int jj = 0; jj < 4; ++jj) {
                const int c = tx * 8 + j + jj;
                float x = acc[i][j + jj] + bias[c];
                if (lrelu) x = (x > 0.f) ? x : NEG_SLOPE * x;
                op[jj] = x;
            }
            *(float4*)(D + (size_t)gr * 128 + tx * 8 + j) = o;
        }
    }
}

// ---------------------------------------------------------------------------
// Fused Q/K/V projection: three GEMMs sharing the A-tile staging.
// ---------------------------------------------------------------------------
__global__ __launch_bounds__(256) void gemm_qkv(
    const float* __restrict__ A,
    const float* __restrict__ W0, const float* __restrict__ W1, const float* __restrict__ W2,
    const float* __restrict__ b0, const float* __restrict__ b1, const float* __restrict__ b2,
    float* __restrict__ D0, float* __restrict__ D1, float* __restrict__ D2, int V)
{
    __shared__ float As[32][65];
    __shared__ float Bs[3][32][128];
    const int tid = threadIdx.x;
    const int tx = tid & 15;
    const int ty = tid >> 4;
    const int row0 = blockIdx.x * 64;
    const float* Ws[3] = {W0, W1, W2};
    const float* bs[3] = {b0, b1, b2};
    float* Ds[3] = {D0, D1, D2};

    float acc[3][4][8];
#pragma unroll
    for (int m = 0; m < 3; ++m)
#pragma unroll
        for (int i = 0; i < 4; ++i)
#pragma unroll
            for (int j = 0; j < 8; ++j) acc[m][i][j] = 0.f;

    for (int k0 = 0; k0 < 128; k0 += 32) {
        {
            const int c = (tid & 7) * 4;
#pragma unroll
            for (int p = 0; p < 2; ++p) {
                const int r = (tid >> 3) + 32 * p;
                const int gr = row0 + r;
                float4 a = make_float4(0.f, 0.f, 0.f, 0.f);
                if (gr < V) a = *(const float4*)(A + (size_t)gr * 128 + k0 + c);
                As[c + 0][r] = a.x; As[c + 1][r] = a.y;
                As[c + 2][r] = a.z; As[c + 3][r] = a.w;
            }
        }
        {
            const int r = tid >> 5;
            const int c = (tid & 31) * 4;
#pragma unroll
            for (int m = 0; m < 3; ++m)
#pragma unroll
                for (int p = 0; p < 4; ++p) {
                    float4 b = *(const float4*)(Ws[m] + (size_t)(k0 + r + 8 * p) * 128 + c);
                    *(float4*)&Bs[m][r + 8 * p][c] = b;
                }
        }
        __syncthreads();
#pragma unroll 4
        for (int kk = 0; kk < 32; ++kk) {
            float a[4];
#pragma unroll
            for (int i = 0; i < 4; ++i) a[i] = As[kk][ty * 4 + i];
#pragma unroll
            for (int m = 0; m < 3; ++m) {
                const float4 q0 = *(const float4*)&Bs[m][kk][tx * 8];
                const float4 q1 = *(const float4*)&Bs[m][kk][tx * 8 + 4];
                const float b[8] = {q0.x, q0.y, q0.z, q0.w, q1.x, q1.y, q1.z, q1.w};
#pragma unroll
                for (int i = 0; i < 4; ++i)
#pragma unroll
                    for (int j = 0; j < 8; ++j) acc[m][i][j] += a[i] * b[j];
            }
        }
        __syncthreads();
    }

#pragma unroll
    for (int m = 0; m < 3; ++m)
#pragma unroll
        for (int i = 0; i < 4; ++i) {
            const int gr = row0 + ty * 4 + i;
            if (gr >= V) continue;
#pragma unroll
            for (int j = 0; j < 8; j += 4) {
                float4 o;
                float* op = &o.x;
#pragma unroll
                for (int jj = 0; jj < 4; ++jj)
                    op[jj] = acc[m][i][j + jj] + bs[m][tx * 8 + j + jj];
                *(float4*)(Ds[m] + (size_t)gr * 128 + tx * 8 + j) = o;
            }
        }
}

// ---------------------------------------------------------------------------
// Per-target in-degree count
// ---------------------------------------------------------------------------
__global__ __launch_bounds__(256) void count_tgt(const int* __restrict__ tgt,
                                                 int* __restrict__ cnt, int E)
{
    const int e = blockIdx.x * blockDim.x + threadIdx.x;
    if (e < E) atomicAdd(cnt + tgt[e], 1);
}

// ---------------------------------------------------------------------------
// CSR build: block-wise exclusive scan of per-node counts
// ---------------------------------------------------------------------------
__global__ __launch_bounds__(256) void scan1(const int* __restrict__ cnt,
                                             int* __restrict__ offs,
                                             int* __restrict__ bsums, int V)
{
    __shared__ int sh[256];
    const int t = threadIdx.x;
    const int base = blockIdx.x * 1024;
    int v[4];
    int s = 0;
#pragma unroll
    for (int i = 0; i < 4; ++i) {
        const int idx = base + t * 4 + i;
        v[i] = (idx < V) ? cnt[idx] : 0;
        s += v[i];
    }
    sh[t] = s;
    __syncthreads();
    for (int off = 1; off < 256; off <<= 1) {
        const int x = (t >= off) ? sh[t - off] : 0;
        __syncthreads();
        sh[t] += x;
        __syncthreads();
    }
    int run = (t > 0) ? sh[t - 1] : 0;
#pragma unroll
    for (int i = 0; i < 4; ++i) {
        const int idx = base + t * 4 + i;
        if (idx < V) offs[idx] = run;
        run += v[i];
    }
    if (t == 255) bsums[blockIdx.x] = sh[255];
}

__global__ void scan2(int* __restrict__ bsums, int nb)
{
    if (threadIdx.x == 0 && blockIdx.x == 0) {
        int run = 0;
        for (int i = 0; i < nb; ++i) { const int x = bsums[i]; bsums[i] = run; run += x; }
    }
}

__global__ __launch_bounds__(256) void scan3(int* __restrict__ offs,
                                             const int* __restrict__ bsums,
                                             int* __restrict__ fill, int V)
{
    const int v = blockIdx.x * blockDim.x + threadIdx.x;
    if (v >= V) return;
    const int o = offs[v] + bsums[v >> 10];
    offs[v] = o;
    fill[v] = o;
}

// ---------------------------------------------------------------------------
// Scatter edges into target-sorted order: packed (src, edge weight) int2.
// ---------------------------------------------------------------------------
__global__ __launch_bounds__(256) void scatter_edges(
    const int* __restrict__ src, const int* __restrict__ tgt,
    const float* __restrict__ ew, int* __restrict__ fill,
    int2* __restrict__ se, int E)
{
    const int e = blockIdx.x * blockDim.x + threadIdx.x;
    if (e >= E) return;
    const int pos = atomicAdd(fill + tgt[e], 1);
    se[pos] = make_int2(src[e], __float_as_int(ew[e]));
}

// ---------------------------------------------------------------------------
// Fused per-node kernel: QK^T logits + exp + softmax-denominator + weighted
// Vv aggregation + normalization. PERSISTENT WAVES: grid sized to residency,
// each wave pulls node ids from a global counter -> no block-retirement skew,
// achieved occupancy stays high until the pool drains.
// Inner loop = R4 interleaved structure (compiler already overlaps the Vv
// loads with the dot chain; explicit prefetch only burned VGPRs, R5 lesson).
// Ksh padded [4][36]: head h starts at bank 9h%32 -> conflict-free b128 reads.
// ---------------------------------------------------------------------------
__global__ __launch_bounds__(256) void fused_agg(
    const float* __restrict__ Q, const float* __restrict__ K,
    const float* __restrict__ Vv, const int2* __restrict__ se,
    const int* __restrict__ offs, const int* __restrict__ fill,
    const float* __restrict__ Wei, const float* __restrict__ bei,
    float* __restrict__ accum, int* __restrict__ ctr, int V)
{
    __shared__ float Ksh[4][4][36];   // [wave][head][32 padded to 36]
    const int wid = threadIdx.x >> 6;
    const int l   = threadIdx.x & 63;
    const int h   = l & 3;    // stage-A head (lane = jj*4 + h)
    const int hd  = l >> 4;   // stage-B head (lane owns dims 2l,2l+1)
    const float weH = Wei[h], beH = bei[h];
    const float2* __restrict__ Vv2 = (const float2*)Vv;

    for (;;) {
        int node;
        if (l == 0) node = atomicAdd(ctr, 1);
        node = __shfl(node, 0);
        if (node >= V) break;

        // stage K row into padded LDS (wave-local, no barrier needed)
        {
            const float2 kk = *(const float2*)(K + (size_t)node * 128 + l * 2);
            const int f0 = l * 2;
            Ksh[wid][f0 >> 5][f0 & 31] = kk.x;
            Ksh[wid][(f0 + 1) >> 5][(f0 + 1) & 31] = kk.y;
        }

        const int start = offs[node];
        const int end   = fill[node];

        float degacc = 0.f;
        float ax = 0.f, ay = 0.f;

        for (int b0 = start; b0 < end; b0 += 16) {
            const int nj = min(16, end - b0);
            const int jj = l >> 2;
            int   s = 0;
            float w = 0.f, p = 0.f;
            if (jj < nj) {
                const int2 t = se[b0 + jj];
                s = t.x;
                w = __int_as_float(t.y);
                const float4* qp = (const float4*)(Q + (size_t)s * 128 + h * 32);
                float dot = 0.f;
#pragma unroll
                for (int i = 0; i < 8; ++i) {
                    const float4 q = qp[i];
                    const float4 k = *(const float4*)&Ksh[wid][h][i * 4];
                    dot += q.x * k.x + q.y * k.y + q.z * k.z + q.w * k.w;
                }
                float bb = fmaf(w, weH, beH);
                bb = (bb > 0.f) ? bb : NEG_SLOPE * bb;
                p = __expf(fmaf(dot, 0.17677669529663687f, bb));
            }
            degacc += p;
            const float coef = p * w;

            if (nj == 16) {
#pragma unroll
                for (int j = 0; j < 16; ++j) {
                    const float cj = __shfl(coef, j * 4 + hd);
                    const int   sj = __shfl(s,    j * 4);
                    const float2 v = Vv2[(size_t)sj * 64 + l];
                    ax = fmaf(cj, v.x, ax);
                    ay = fmaf(cj, v.y, ay);
                }
            } else {
                for (int j = 0; j < nj; ++j) {
                    const float cj = __shfl(coef, j * 4 + hd);
                    const int   sj = __shfl(s,    j * 4);
                    const float2 v = Vv2[(size_t)sj * 64 + l];
                    ax = fmaf(cj, v.x, ax);
                    ay = fmaf(cj, v.y, ay);
                }
            }
        }

        // reduce degacc across the 16 lanes sharing head (l&3)
        float d = degacc;
        d += __shfl_xor(d, 4);
        d += __shfl_xor(d, 8);
        d += __shfl_xor(d, 16);
        d += __shfl_xor(d, 32);
        const float deg = __shfl(d, hd);   // lane 'hd' holds head hd's sum
        const float inv = 1.0f / (deg + 1e-16f);

        *(float2*)(accum + (size_t)node * 128 + l * 2) =
            make_float2(ax * inv, ay * inv);
    }
}

// ---------------------------------------------------------------------------
extern "C" void kernel_launch(void* const* d_in, const int* in_sizes, int n_in,
                              void* d_out, int out_size, void* d_ws, size_t ws_size,
                              hipStream_t stream)
{
    const float* h   = (const float*)d_in[0];
    const int*   ei  = (const int*)  d_in[1];
    const float* ew  = (const float*)d_in[2];
    const float* Wq  = (const float*)d_in[3];
    const float* bq  = (const float*)d_in[4];
    const float* Wk  = (const float*)d_in[5];
    const float* bk  = (const float*)d_in[6];
    const float* Wv  = (const float*)d_in[7];
    const float* bv  = (const float*)d_in[8];
    const float* Wo  = (const float*)d_in[9];
    const float* bo  = (const float*)d_in[10];
    const float* Wei = (const float*)d_in[11];
    const float* bei = (const float*)d_in[12];

    const int V = in_sizes[0] / 128;
    const int E = in_sizes[2];
    const int* src = ei;
    const int* tgt = ei + E;

    // workspace layout
    float* Q     = (float*)d_ws;
    float* Km    = Q  + (size_t)V * 128;
    float* Vm    = Km + (size_t)V * 128;
    float* accum = Vm + (size_t)V * 128;
    int2*  se    = (int2*)(accum + (size_t)V * 128);
    int*   cnt   = (int*)(se + E);
    int*   ctr   = cnt + V;          // ctr adjacent to cnt: one memset
    int*   offs  = ctr + 1;
    int*   fill  = offs + V + 1;
    int*   bsums = fill + V;

    hipMemsetAsync(cnt, 0, (size_t)(V + 1) * sizeof(int), stream);  // cnt + ctr

    const int gemmGrid = (V + 63) / 64;
    gemm_qkv<<<gemmGrid, 256, 0, stream>>>(h, Wq, Wk, Wv, bq, bk, bv, Q, Km, Vm, V);

    count_tgt<<<(E + 255) / 256, 256, 0, stream>>>(tgt, cnt, E);
    const int nb = (V + 1023) / 1024;
    scan1<<<nb, 256, 0, stream>>>(cnt, offs, bsums, V);
    scan2<<<1, 64, 0, stream>>>(bsums, nb);
    scan3<<<(V + 255) / 256, 256, 0, stream>>>(offs, bsums, fill, V);
    scatter_edges<<<(E + 255) / 256, 256, 0, stream>>>(
        src, tgt, ew, fill, se, E);

    // persistent: 8 blocks/CU x 256 CUs
    fused_agg<<<2048, 256, 0, stream>>>(
        Q, Km, Vm, se, offs, fill, Wei, bei, accum, ctr, V);

    gemm128<<<gemmGrid, 256, 0, stream>>>(accum, Wo, bo, (float*)d_out, V, 1);
}

// Round 8
// 347.802 us; speedup vs baseline: 2.5963x; 2.5963x over previous
//
#include <hip/hip_runtime.h>
#include <hip/hip_bf16.h>

#define NEG_SLOPE 0.2f

// ---------------------------------------------------------------------------
// Tiled f32 GEMM: D[V,128] = act(A[V,128] @ W[128,128] + bias), optional lrelu
// ---------------------------------------------------------------------------
__global__ __launch_bounds__(256) void gemm128(const float* __restrict__ A,
                                               const float* __restrict__ W,
                                               const float* __restrict__ bias,
                                               float* __restrict__ D,
                                               int V, int lrelu)
{
    __shared__ float As[32][65];    // transposed [k][row], padded
    __shared__ float Bs[32][128];   // [k][col]
    const int tid = threadIdx.x;
    const int tx = tid & 15;
    const int ty = tid >> 4;
    const int row0 = blockIdx.x * 64;

    float acc[4][8];
#pragma unroll
    for (int i = 0; i < 4; ++i)
#pragma unroll
        for (int j = 0; j < 8; ++j) acc[i][j] = 0.f;

    for (int k0 = 0; k0 < 128; k0 += 32) {
        {
            const int c = (tid & 7) * 4;
#pragma unroll
            for (int p = 0; p < 2; ++p) {
                const int r = (tid >> 3) + 32 * p;
                const int gr = row0 + r;
                float4 a = make_float4(0.f, 0.f, 0.f, 0.f);
                if (gr < V) a = *(const float4*)(A + (size_t)gr * 128 + k0 + c);
                As[c + 0][r] = a.x; As[c + 1][r] = a.y;
                As[c + 2][r] = a.z; As[c + 3][r] = a.w;
            }
        }
        {
            const int r = tid >> 5;
            const int c = (tid & 31) * 4;
#pragma unroll
            for (int p = 0; p < 4; ++p) {
                float4 b = *(const float4*)(W + (size_t)(k0 + r + 8 * p) * 128 + c);
                *(float4*)&Bs[r + 8 * p][c] = b;
            }
        }
        __syncthreads();
#pragma unroll 8
        for (int kk = 0; kk < 32; ++kk) {
            float a[4];
#pragma unroll
            for (int i = 0; i < 4; ++i) a[i] = As[kk][ty * 4 + i];
            const float4 b0 = *(const float4*)&Bs[kk][tx * 8];
            const float4 b1 = *(const float4*)&Bs[kk][tx * 8 + 4];
            const float b[8] = {b0.x, b0.y, b0.z, b0.w, b1.x, b1.y, b1.z, b1.w};
#pragma unroll
            for (int i = 0; i < 4; ++i)
#pragma unroll
                for (int j = 0; j < 8; ++j) acc[i][j] += a[i] * b[j];
        }
        __syncthreads();
    }

#pragma unroll
    for (int i = 0; i < 4; ++i) {
        const int gr = row0 + ty * 4 + i;
        if (gr >= V) continue;
#pragma unroll
        for (int j = 0; j < 8; j += 4) {
            float4 o;
            float* op = &o.x;
#pragma unroll
            for (int jj = 0; jj < 4; ++jj) {
                const int c = tx * 8 + j + jj;
                float x = acc[i][j + jj] + bias[c];
                if (lrelu) x = (x > 0.f) ? x : NEG_SLOPE * x;
                op[jj] = x;
            }
            *(float4*)(D + (size_t)gr * 128 + tx * 8 + j) = o;
        }
    }
}

// ---------------------------------------------------------------------------
// Fused Q/K/V projection: three GEMMs sharing the A-tile staging. All f32
// (R7 lesson: threshold 0.036 vs output scale ~488 demands ~7e-5 relative
// accuracy -- bf16 anywhere in the data path fails).
// ---------------------------------------------------------------------------
__global__ __launch_bounds__(256) void gemm_qkv(
    const float* __restrict__ A,
    const float* __restrict__ W0, const float* __restrict__ W1, const float* __restrict__ W2,
    const float* __restrict__ b0, const float* __restrict__ b1, const float* __restrict__ b2,
    float* __restrict__ D0, float* __restrict__ D1, float* __restrict__ D2, int V)
{
    __shared__ float As[32][65];
    __shared__ float Bs[3][32][128];
    const int tid = threadIdx.x;
    const int tx = tid & 15;
    const int ty = tid >> 4;
    const int row0 = blockIdx.x * 64;
    const float* Ws[3] = {W0, W1, W2};
    const float* bs[3] = {b0, b1, b2};
    float* Ds[3] = {D0, D1, D2};

    float acc[3][4][8];
#pragma unroll
    for (int m = 0; m < 3; ++m)
#pragma unroll
        for (int i = 0; i < 4; ++i)
#pragma unroll
            for (int j = 0; j < 8; ++j) acc[m][i][j] = 0.f;

    for (int k0 = 0; k0 < 128; k0 += 32) {
        {
            const int c = (tid & 7) * 4;
#pragma unroll
            for (int p = 0; p < 2; ++p) {
                const int r = (tid >> 3) + 32 * p;
                const int gr = row0 + r;
                float4 a = make_float4(0.f, 0.f, 0.f, 0.f);
                if (gr < V) a = *(const float4*)(A + (size_t)gr * 128 + k0 + c);
                As[c + 0][r] = a.x; As[c + 1][r] = a.y;
                As[c + 2][r] = a.z; As[c + 3][r] = a.w;
            }
        }
        {
            const int r = tid >> 5;
            const int c = (tid & 31) * 4;
#pragma unroll
            for (int m = 0; m < 3; ++m)
#pragma unroll
                for (int p = 0; p < 4; ++p) {
                    float4 b = *(const float4*)(Ws[m] + (size_t)(k0 + r + 8 * p) * 128 + c);
                    *(float4*)&Bs[m][r + 8 * p][c] = b;
                }
        }
        __syncthreads();
#pragma unroll 4
        for (int kk = 0; kk < 32; ++kk) {
            float a[4];
#pragma unroll
            for (int i = 0; i < 4; ++i) a[i] = As[kk][ty * 4 + i];
#pragma unroll
            for (int m = 0; m < 3; ++m) {
                const float4 q0 = *(const float4*)&Bs[m][kk][tx * 8];
                const float4 q1 = *(const float4*)&Bs[m][kk][tx * 8 + 4];
                const float b[8] = {q0.x, q0.y, q0.z, q0.w, q1.x, q1.y, q1.z, q1.w};
#pragma unroll
                for (int i = 0; i < 4; ++i)
#pragma unroll
                    for (int j = 0; j < 8; ++j) acc[m][i][j] += a[i] * b[j];
            }
        }
        __syncthreads();
    }

#pragma unroll
    for (int m = 0; m < 3; ++m)
#pragma unroll
        for (int i = 0; i < 4; ++i) {
            const int gr = row0 + ty * 4 + i;
            if (gr >= V) continue;
#pragma unroll
            for (int j = 0; j < 8; j += 4) {
                float4 o;
                float* op = &o.x;
#pragma unroll
                for (int jj = 0; jj < 4; ++jj)
                    op[jj] = acc[m][i][j + jj] + bs[m][tx * 8 + jj + j];
                *(float4*)(Ds[m] + (size_t)gr * 128 + tx * 8 + j) = o;
            }
        }
}

// ---------------------------------------------------------------------------
// Per-target in-degree count
// ---------------------------------------------------------------------------
__global__ __launch_bounds__(256) void count_tgt(const int* __restrict__ tgt,
                                                 int* __restrict__ cnt, int E)
{
    const int e = blockIdx.x * blockDim.x + threadIdx.x;
    if (e < E) atomicAdd(cnt + tgt[e], 1);
}

// ---------------------------------------------------------------------------
// CSR build: block-wise exclusive scan of per-node counts
// ---------------------------------------------------------------------------
__global__ __launch_bounds__(256) void scan1(const int* __restrict__ cnt,
                                             int* __restrict__ offs,
                                             int* __restrict__ bsums, int V)
{
    __shared__ int sh[256];
    const int t = threadIdx.x;
    const int base = blockIdx.x * 1024;
    int v[4];
    int s = 0;
#pragma unroll
    for (int i = 0; i < 4; ++i) {
        const int idx = base + t * 4 + i;
        v[i] = (idx < V) ? cnt[idx] : 0;
        s += v[i];
    }
    sh[t] = s;
    __syncthreads();
    for (int off = 1; off < 256; off <<= 1) {
        const int x = (t >= off) ? sh[t - off] : 0;
        __syncthreads();
        sh[t] += x;
        __syncthreads();
    }
    int run = (t > 0) ? sh[t - 1] : 0;
#pragma unroll
    for (int i = 0; i < 4; ++i) {
        const int idx = base + t * 4 + i;
        if (idx < V) offs[idx] = run;
        run += v[i];
    }
    if (t == 255) bsums[blockIdx.x] = sh[255];
}

__global__ void scan2(int* __restrict__ bsums, int nb)
{
    if (threadIdx.x == 0 && blockIdx.x == 0) {
        int run = 0;
        for (int i = 0; i < nb; ++i) { const int x = bsums[i]; bsums[i] = run; run += x; }
    }
}

__global__ __launch_bounds__(256) void scan3(int* __restrict__ offs,
                                             const int* __restrict__ bsums,
                                             int* __restrict__ fill, int V)
{
    const int v = blockIdx.x * blockDim.x + threadIdx.x;
    if (v >= V) return;
    const int o = offs[v] + bsums[v >> 10];
    offs[v] = o;
    fill[v] = o;
}

// ---------------------------------------------------------------------------
// Scatter edges into target-sorted order: packed (src, edge weight) int2.
// ---------------------------------------------------------------------------
__global__ __launch_bounds__(256) void scatter_edges(
    const int* __restrict__ src, const int* __restrict__ tgt,
    const float* __restrict__ ew, int* __restrict__ fill,
    int2* __restrict__ se, int E)
{
    const int e = blockIdx.x * blockDim.x + threadIdx.x;
    if (e >= E) return;
    const int pos = atomicAdd(fill + tgt[e], 1);
    se[pos] = make_int2(src[e], __float_as_int(ew[e]));
}

// ---------------------------------------------------------------------------
// Fused per-node kernel (all f32): QK^T + exp + denom + weighted Vv
// aggregation + normalization. One wave per node, GRID-STRIDE persistent:
//   - no atomics (R6 lesson: same-address atomic scheduler serializes 5x)
//   - ~6 nodes/wave evens Poisson-degree skew vs R4's 1 node/wave static map
// Inner loop = R4 interleaved structure (R5 lesson: explicit prefetch only
// burned VGPRs). Ksh padded [4][36]: conflict-free b128 broadcast reads.
// ---------------------------------------------------------------------------
__global__ __launch_bounds__(256) void fused_agg(
    const float* __restrict__ Q, const float* __restrict__ K,
    const float* __restrict__ Vv, const int2* __restrict__ se,
    const int* __restrict__ offs, const int* __restrict__ fill,
    const float* __restrict__ Wei, const float* __restrict__ bei,
    float* __restrict__ accum, int V)
{
    __shared__ float Ksh[4][4][36];   // [wave][head][32 padded to 36]
    const int wid = threadIdx.x >> 6;
    const int l   = threadIdx.x & 63;
    const int h   = l & 3;    // stage-A head (lane = jj*4 + h)
    const int hd  = l >> 4;   // stage-B head (lane owns dims 2l,2l+1)
    const float weH = Wei[h], beH = bei[h];
    const float2* __restrict__ Vv2 = (const float2*)Vv;

    const int nwaves = gridDim.x * 4;
    const int gw     = blockIdx.x * 4 + wid;

    for (int node = gw; node < V; node += nwaves) {
        // stage K row into padded LDS (wave-local, no barrier needed)
        {
            const float2 kk = *(const float2*)(K + (size_t)node * 128 + l * 2);
            const int f0 = l * 2;
            Ksh[wid][f0 >> 5][f0 & 31] = kk.x;
            Ksh[wid][(f0 + 1) >> 5][(f0 + 1) & 31] = kk.y;
        }

        const int start = offs[node];
        const int end   = fill[node];

        float degacc = 0.f;
        float ax = 0.f, ay = 0.f;

        for (int b0 = start; b0 < end; b0 += 16) {
            const int nj = min(16, end - b0);
            const int jj = l >> 2;
            int   s = 0;
            float w = 0.f, p = 0.f;
            if (jj < nj) {
                const int2 t = se[b0 + jj];
                s = t.x;
                w = __int_as_float(t.y);
                const float4* qp = (const float4*)(Q + (size_t)s * 128 + h * 32);
                float dot = 0.f;
#pragma unroll
                for (int i = 0; i < 8; ++i) {
                    const float4 q = qp[i];
                    const float4 k = *(const float4*)&Ksh[wid][h][i * 4];
                    dot += q.x * k.x + q.y * k.y + q.z * k.z + q.w * k.w;
                }
                float bb = fmaf(w, weH, beH);
                bb = (bb > 0.f) ? bb : NEG_SLOPE * bb;
                p = __expf(fmaf(dot, 0.17677669529663687f, bb));
            }
            degacc += p;
            const float coef = p * w;

            if (nj == 16) {
#pragma unroll
                for (int j = 0; j < 16; ++j) {
                    const float cj = __shfl(coef, j * 4 + hd);
                    const int   sj = __shfl(s,    j * 4);
                    const float2 v = Vv2[(size_t)sj * 64 + l];
                    ax = fmaf(cj, v.x, ax);
                    ay = fmaf(cj, v.y, ay);
                }
            } else {
                for (int j = 0; j < nj; ++j) {
                    const float cj = __shfl(coef, j * 4 + hd);
                    const int   sj = __shfl(s,    j * 4);
                    const float2 v = Vv2[(size_t)sj * 64 + l];
                    ax = fmaf(cj, v.x, ax);
                    ay = fmaf(cj, v.y, ay);
                }
            }
        }

        // reduce degacc across the 16 lanes sharing head (l&3)
        float d = degacc;
        d += __shfl_xor(d, 4);
        d += __shfl_xor(d, 8);
        d += __shfl_xor(d, 16);
        d += __shfl_xor(d, 32);
        const float deg = __shfl(d, hd);   // lane 'hd' holds head hd's sum
        const float inv = 1.0f / (deg + 1e-16f);

        *(float2*)(accum + (size_t)node * 128 + l * 2) =
            make_float2(ax * inv, ay * inv);
    }
}

// ---------------------------------------------------------------------------
extern "C" void kernel_launch(void* const* d_in, const int* in_sizes, int n_in,
                              void* d_out, int out_size, void* d_ws, size_t ws_size,
                              hipStream_t stream)
{
    const float* h   = (const float*)d_in[0];
    const int*   ei  = (const int*)  d_in[1];
    const float* ew  = (const float*)d_in[2];
    const float* Wq  = (const float*)d_in[3];
    const float* bq  = (const float*)d_in[4];
    const float* Wk  = (const float*)d_in[5];
    const float* bk  = (const float*)d_in[6];
    const float* Wv  = (const float*)d_in[7];
    const float* bv  = (const float*)d_in[8];
    const float* Wo  = (const float*)d_in[9];
    const float* bo  = (const float*)d_in[10];
    const float* Wei = (const float*)d_in[11];
    const float* bei = (const float*)d_in[12];

    const int V = in_sizes[0] / 128;
    const int E = in_sizes[2];
    const int* src = ei;
    const int* tgt = ei + E;

    // workspace layout
    float* Q     = (float*)d_ws;
    float* Km    = Q  + (size_t)V * 128;
    float* Vm    = Km + (size_t)V * 128;
    float* accum = Vm + (size_t)V * 128;
    int2*  se    = (int2*)(accum + (size_t)V * 128);
    int*   cnt   = (int*)(se + E);
    int*   offs  = cnt  + V;
    int*   fill  = offs + V + 1;
    int*   bsums = fill + V;

    hipMemsetAsync(cnt, 0, (size_t)V * sizeof(int), stream);

    const int gemmGrid = (V + 63) / 64;
    gemm_qkv<<<gemmGrid, 256, 0, stream>>>(h, Wq, Wk, Wv, bq, bk, bv, Q, Km, Vm, V);

    count_tgt<<<(E + 255) / 256, 256, 0, stream>>>(tgt, cnt, E);
    const int nb = (V + 1023) / 1024;
    scan1<<<nb, 256, 0, stream>>>(cnt, offs, bsums, V);
    scan2<<<1, 64, 0, stream>>>(bsums, nb);
    scan3<<<(V + 255) / 256, 256, 0, stream>>>(offs, bsums, fill, V);
    scatter_edges<<<(E + 255) / 256, 256, 0, stream>>>(
        src, tgt, ew, fill, se, E);

    // persistent grid-stride: 2048 blocks = 8192 waves, ~6 nodes/wave
    fused_agg<<<2048, 256, 0, stream>>>(
        Q, Km, Vm, se, offs, fill, Wei, bei, accum, V);

    gemm128<<<gemmGrid, 256, 0, stream>>>(accum, Wo, bo, (float*)d_out, V, 1);
}

// Round 9
// 319.020 us; speedup vs baseline: 2.8306x; 1.0902x over previous
//
#include <hip/hip_runtime.h>
#include <hip/hip_bf16.h>

#define NEG_SLOPE 0.2f

// ---------------------------------------------------------------------------
// f32 GEMM, BM=128 BN=128 BK=16, 256 threads, 8x8 micro-tile.
// 64 FMA per 4 LDS b128 reads per kk (vs 32:3 in the old 4x8 tile).
// As[16][136]: 544B row stride, 16B aligned, 4 distinct b128 addrs/wave -> CF.
// Bs[16][192]: col-block c' stored at c'*12 -> 16 addrs, 2-way max (free).
// QKV fusion via gridDim.y: W/b/D selected per block (wave-uniform).
// ---------------------------------------------------------------------------
__global__ __launch_bounds__(256) void gemm_big(
    const float* __restrict__ A,
    const float* __restrict__ W0, const float* __restrict__ W1, const float* __restrict__ W2,
    const float* __restrict__ b0, const float* __restrict__ b1, const float* __restrict__ b2,
    float* __restrict__ D0, float* __restrict__ D1, float* __restrict__ D2,
    int V, int lrelu)
{
    __shared__ float As[16][136];   // [k][row], 8.7 KB
    __shared__ float Bs[16][192];   // [k][col-block*12], 12 KB

    const int m = blockIdx.y;
    const float* __restrict__ W  = (m == 0) ? W0 : ((m == 1) ? W1 : W2);
    const float* __restrict__ bb = (m == 0) ? b0 : ((m == 1) ? b1 : b2);
    float* __restrict__ D        = (m == 0) ? D0 : ((m == 1) ? D1 : D2);

    const int tid = threadIdx.x;
    const int tx = tid & 15;        // col block: cols tx*8..+7
    const int ty = tid >> 4;        // row block: rows ty*8..+7
    const int row0 = blockIdx.x * 128;

    // staging indices
    const int ar = tid >> 1;            // 0..127: A row
    const int ak = (tid & 1) * 8;       // 0/8: A k-offset
    const int bk = tid >> 4;            // 0..15: B k-row
    const int bc = tid & 15;            // 0..15: B col-block

    float acc[8][8];
#pragma unroll
    for (int i = 0; i < 8; ++i)
#pragma unroll
        for (int j = 0; j < 8; ++j) acc[i][j] = 0.f;

    for (int k0 = 0; k0 < 128; k0 += 16) {
        // stage A tile (128 rows x 16 k), transposed
        {
            const int gr = row0 + ar;
            float4 a0 = make_float4(0.f, 0.f, 0.f, 0.f);
            float4 a1 = make_float4(0.f, 0.f, 0.f, 0.f);
            if (gr < V) {
                a0 = *(const float4*)(A + (size_t)gr * 128 + k0 + ak);
                a1 = *(const float4*)(A + (size_t)gr * 128 + k0 + ak + 4);
            }
            As[ak + 0][ar] = a0.x; As[ak + 1][ar] = a0.y;
            As[ak + 2][ar] = a0.z; As[ak + 3][ar] = a0.w;
            As[ak + 4][ar] = a1.x; As[ak + 5][ar] = a1.y;
            As[ak + 6][ar] = a1.z; As[ak + 7][ar] = a1.w;
        }
        // stage B tile (16 k x 128 cols), 12-stride col blocks
        {
            const float4 w0 = *(const float4*)(W + (size_t)(k0 + bk) * 128 + bc * 8);
            const float4 w1 = *(const float4*)(W + (size_t)(k0 + bk) * 128 + bc * 8 + 4);
            *(float4*)&Bs[bk][bc * 12]     = w0;
            *(float4*)&Bs[bk][bc * 12 + 4] = w1;
        }
        __syncthreads();
#pragma unroll
        for (int kk = 0; kk < 16; ++kk) {
            float a[8], b[8];
            *(float4*)&a[0] = *(const float4*)&As[kk][ty * 8];
            *(float4*)&a[4] = *(const float4*)&As[kk][ty * 8 + 4];
            *(float4*)&b[0] = *(const float4*)&Bs[kk][tx * 12];
            *(float4*)&b[4] = *(const float4*)&Bs[kk][tx * 12 + 4];
#pragma unroll
            for (int i = 0; i < 8; ++i)
#pragma unroll
                for (int j = 0; j < 8; ++j) acc[i][j] = fmaf(a[i], b[j], acc[i][j]);
        }
        __syncthreads();
    }

    // epilogue: bias + optional lrelu
#pragma unroll
    for (int i = 0; i < 8; ++i) {
        const int gr = row0 + ty * 8 + i;
        if (gr >= V) continue;
#pragma unroll
        for (int j = 0; j < 8; j += 4) {
            float4 o;
            float* op = &o.x;
#pragma unroll
            for (int jj = 0; jj < 4; ++jj) {
                float x = acc[i][j + jj] + bb[tx * 8 + j + jj];
                if (lrelu) x = (x > 0.f) ? x : NEG_SLOPE * x;
                op[jj] = x;
            }
            *(float4*)(D + (size_t)gr * 128 + tx * 8 + j) = o;
        }
    }
}

// ---------------------------------------------------------------------------
// Per-target in-degree count
// ---------------------------------------------------------------------------
__global__ __launch_bounds__(256) void count_tgt(const int* __restrict__ tgt,
                                                 int* __restrict__ cnt, int E)
{
    const int e = blockIdx.x * blockDim.x + threadIdx.x;
    if (e < E) atomicAdd(cnt + tgt[e], 1);
}

// ---------------------------------------------------------------------------
// CSR build: block-wise exclusive scan of per-node counts
// ---------------------------------------------------------------------------
__global__ __launch_bounds__(256) void scan1(const int* __restrict__ cnt,
                                             int* __restrict__ offs,
                                             int* __restrict__ bsums, int V)
{
    __shared__ int sh[256];
    const int t = threadIdx.x;
    const int base = blockIdx.x * 1024;
    int v[4];
    int s = 0;
#pragma unroll
    for (int i = 0; i < 4; ++i) {
        const int idx = base + t * 4 + i;
        v[i] = (idx < V) ? cnt[idx] : 0;
        s += v[i];
    }
    sh[t] = s;
    __syncthreads();
    for (int off = 1; off < 256; off <<= 1) {
        const int x = (t >= off) ? sh[t - off] : 0;
        __syncthreads();
        sh[t] += x;
        __syncthreads();
    }
    int run = (t > 0) ? sh[t - 1] : 0;
#pragma unroll
    for (int i = 0; i < 4; ++i) {
        const int idx = base + t * 4 + i;
        if (idx < V) offs[idx] = run;
        run += v[i];
    }
    if (t == 255) bsums[blockIdx.x] = sh[255];
}

__global__ void scan2(int* __restrict__ bsums, int nb)
{
    if (threadIdx.x == 0 && blockIdx.x == 0) {
        int run = 0;
        for (int i = 0; i < nb; ++i) { const int x = bsums[i]; bsums[i] = run; run += x; }
    }
}

__global__ __launch_bounds__(256) void scan3(int* __restrict__ offs,
                                             const int* __restrict__ bsums,
                                             int* __restrict__ fill, int V)
{
    const int v = blockIdx.x * blockDim.x + threadIdx.x;
    if (v >= V) return;
    const int o = offs[v] + bsums[v >> 10];
    offs[v] = o;
    fill[v] = o;
}

// ---------------------------------------------------------------------------
// Scatter edges into target-sorted order: packed (src, edge weight) int2.
// ---------------------------------------------------------------------------
__global__ __launch_bounds__(256) void scatter_edges(
    const int* __restrict__ src, const int* __restrict__ tgt,
    const float* __restrict__ ew, int* __restrict__ fill,
    int2* __restrict__ se, int E)
{
    const int e = blockIdx.x * blockDim.x + threadIdx.x;
    if (e >= E) return;
    const int pos = atomicAdd(fill + tgt[e], 1);
    se[pos] = make_int2(src[e], __float_as_int(ew[e]));
}

// ---------------------------------------------------------------------------
// Fused per-node kernel (all f32): QK^T + exp + denom + weighted Vv
// aggregation + normalization. One wave per node, STATIC mapping
// (R8 lesson: grid-stride persistence scattered se/K/accum locality and
// lost 10 us vs static; R6 lesson: atomic scheduler serializes 5x).
// Ksh padded [4][36]: conflict-free b128 broadcast reads (R5 win).
// ---------------------------------------------------------------------------
__global__ __launch_bounds__(256) void fused_agg(
    const float* __restrict__ Q, const float* __restrict__ K,
    const float* __restrict__ Vv, const int2* __restrict__ se,
    const int* __restrict__ offs, const int* __restrict__ fill,
    const float* __restrict__ Wei, const float* __restrict__ bei,
    float* __restrict__ accum, int V)
{
    __shared__ float Ksh[4][4][36];   // [wave][head][32 padded to 36]
    const int wid = threadIdx.x >> 6;
    const int node = blockIdx.x * 4 + wid;
    if (node >= V) return;
    const int l   = threadIdx.x & 63;
    const int h   = l & 3;    // stage-A head (lane = jj*4 + h)
    const int hd  = l >> 4;   // stage-B head (lane owns dims 2l,2l+1)
    const float weH = Wei[h], beH = bei[h];
    const float2* __restrict__ Vv2 = (const float2*)Vv;

    // stage K row into padded LDS (wave-local, no barrier needed)
    {
        const float2 kk = *(const float2*)(K + (size_t)node * 128 + l * 2);
        const int f0 = l * 2;
        Ksh[wid][f0 >> 5][f0 & 31] = kk.x;
        Ksh[wid][(f0 + 1) >> 5][(f0 + 1) & 31] = kk.y;
    }

    const int start = offs[node];
    const int end   = fill[node];

    float degacc = 0.f;
    float ax = 0.f, ay = 0.f;

    for (int b0 = start; b0 < end; b0 += 16) {
        const int nj = min(16, end - b0);
        const int jj = l >> 2;
        int   s = 0;
        float w = 0.f, p = 0.f;
        if (jj < nj) {
            const int2 t = se[b0 + jj];
            s = t.x;
            w = __int_as_float(t.y);
            const float4* qp = (const float4*)(Q + (size_t)s * 128 + h * 32);
            float dot = 0.f;
#pragma unroll
            for (int i = 0; i < 8; ++i) {
                const float4 q = qp[i];
                const float4 k = *(const float4*)&Ksh[wid][h][i * 4];
                dot += q.x * k.x + q.y * k.y + q.z * k.z + q.w * k.w;
            }
            float bb = fmaf(w, weH, beH);
            bb = (bb > 0.f) ? bb : NEG_SLOPE * bb;
            p = __expf(fmaf(dot, 0.17677669529663687f, bb));
        }
        degacc += p;
        const float coef = p * w;

        if (nj == 16) {
#pragma unroll
            for (int j = 0; j < 16; ++j) {
                const float cj = __shfl(coef, j * 4 + hd);
                const int   sj = __shfl(s,    j * 4);
                const float2 v = Vv2[(size_t)sj * 64 + l];
                ax = fmaf(cj, v.x, ax);
                ay = fmaf(cj, v.y, ay);
            }
        } else {
            for (int j = 0; j < nj; ++j) {
                const float cj = __shfl(coef, j * 4 + hd);
                const int   sj = __shfl(s,    j * 4);
                const float2 v = Vv2[(size_t)sj * 64 + l];
                ax = fmaf(cj, v.x, ax);
                ay = fmaf(cj, v.y, ay);
            }
        }
    }

    // reduce degacc across the 16 lanes sharing head (l&3)
    float d = degacc;
    d += __shfl_xor(d, 4);
    d += __shfl_xor(d, 8);
    d += __shfl_xor(d, 16);
    d += __shfl_xor(d, 32);
    const float deg = __shfl(d, hd);   // lane 'hd' holds head hd's sum
    const float inv = 1.0f / (deg + 1e-16f);

    *(float2*)(accum + (size_t)node * 128 + l * 2) =
        make_float2(ax * inv, ay * inv);
}

// ---------------------------------------------------------------------------
extern "C" void kernel_launch(void* const* d_in, const int* in_sizes, int n_in,
                              void* d_out, int out_size, void* d_ws, size_t ws_size,
                              hipStream_t stream)
{
    const float* h   = (const float*)d_in[0];
    const int*   ei  = (const int*)  d_in[1];
    const float* ew  = (const float*)d_in[2];
    const float* Wq  = (const float*)d_in[3];
    const float* bq  = (const float*)d_in[4];
    const float* Wk  = (const float*)d_in[5];
    const float* bk  = (const float*)d_in[6];
    const float* Wv  = (const float*)d_in[7];
    const float* bv  = (const float*)d_in[8];
    const float* Wo  = (const float*)d_in[9];
    const float* bo  = (const float*)d_in[10];
    const float* Wei = (const float*)d_in[11];
    const float* bei = (const float*)d_in[12];

    const int V = in_sizes[0] / 128;
    const int E = in_sizes[2];
    const int* src = ei;
    const int* tgt = ei + E;

    // workspace layout
    float* Q     = (float*)d_ws;
    float* Km    = Q  + (size_t)V * 128;
    float* Vm    = Km + (size_t)V * 128;
    float* accum = Vm + (size_t)V * 128;
    int2*  se    = (int2*)(accum + (size_t)V * 128);
    int*   cnt   = (int*)(se + E);
    int*   offs  = cnt  + V;
    int*   fill  = offs + V + 1;
    int*   bsums = fill + V;

    hipMemsetAsync(cnt, 0, (size_t)V * sizeof(int), stream);

    const int bigGrid = (V + 127) / 128;
    gemm_big<<<dim3(bigGrid, 3), 256, 0, stream>>>(
        h, Wq, Wk, Wv, bq, bk, bv, Q, Km, Vm, V, 0);

    count_tgt<<<(E + 255) / 256, 256, 0, stream>>>(tgt, cnt, E);
    const int nb = (V + 1023) / 1024;
    scan1<<<nb, 256, 0, stream>>>(cnt, offs, bsums, V);
    scan2<<<1, 64, 0, stream>>>(bsums, nb);
    scan3<<<(V + 255) / 256, 256, 0, stream>>>(offs, bsums, fill, V);
    scatter_edges<<<(E + 255) / 256, 256, 0, stream>>>(
        src, tgt, ew, fill, se, E);

    fused_agg<<<(V + 3) / 4, 256, 0, stream>>>(
        Q, Km, Vm, se, offs, fill, Wei, bei, accum, V);

    gemm_big<<<dim3(bigGrid, 1), 256, 0, stream>>>(
        accum, Wo, Wo, Wo, bo, bo, bo, (float*)d_out, (float*)d_out, (float*)d_out, V, 1);
}

// Round 10
// 318.823 us; speedup vs baseline: 2.8323x; 1.0006x over previous
//
#include <hip/hip_runtime.h>
#include <hip/hip_bf16.h>

#define NEG_SLOPE 0.2f

// ---------------------------------------------------------------------------
// f32 GEMM, BM=128 BN=128 BK=16, 256 threads, 8x8 micro-tile.
// As[16][136]: 544B row stride, 16B aligned, 4 distinct b128 addrs/wave -> CF.
// Bs[16][192]: col-block c' stored at c'*12 -> 16 addrs, 2-way max (free).
// QKV fusion via gridDim.y: W/b/D selected per block (wave-uniform).
// ---------------------------------------------------------------------------
__global__ __launch_bounds__(256) void gemm_big(
    const float* __restrict__ A,
    const float* __restrict__ W0, const float* __restrict__ W1, const float* __restrict__ W2,
    const float* __restrict__ b0, const float* __restrict__ b1, const float* __restrict__ b2,
    float* __restrict__ D0, float* __restrict__ D1, float* __restrict__ D2,
    int V, int lrelu)
{
    __shared__ float As[16][136];   // [k][row], 8.7 KB
    __shared__ float Bs[16][192];   // [k][col-block*12], 12 KB

    const int m = blockIdx.y;
    const float* __restrict__ W  = (m == 0) ? W0 : ((m == 1) ? W1 : W2);
    const float* __restrict__ bb = (m == 0) ? b0 : ((m == 1) ? b1 : b2);
    float* __restrict__ D        = (m == 0) ? D0 : ((m == 1) ? D1 : D2);

    const int tid = threadIdx.x;
    const int tx = tid & 15;        // col block: cols tx*8..+7
    const int ty = tid >> 4;        // row block: rows ty*8..+7
    const int row0 = blockIdx.x * 128;

    // staging indices
    const int ar = tid >> 1;            // 0..127: A row
    const int ak = (tid & 1) * 8;       // 0/8: A k-offset
    const int bk = tid >> 4;            // 0..15: B k-row
    const int bc = tid & 15;            // 0..15: B col-block

    float acc[8][8];
#pragma unroll
    for (int i = 0; i < 8; ++i)
#pragma unroll
        for (int j = 0; j < 8; ++j) acc[i][j] = 0.f;

    for (int k0 = 0; k0 < 128; k0 += 16) {
        {
            const int gr = row0 + ar;
            float4 a0 = make_float4(0.f, 0.f, 0.f, 0.f);
            float4 a1 = make_float4(0.f, 0.f, 0.f, 0.f);
            if (gr < V) {
                a0 = *(const float4*)(A + (size_t)gr * 128 + k0 + ak);
                a1 = *(const float4*)(A + (size_t)gr * 128 + k0 + ak + 4);
            }
            As[ak + 0][ar] = a0.x; As[ak + 1][ar] = a0.y;
            As[ak + 2][ar] = a0.z; As[ak + 3][ar] = a0.w;
            As[ak + 4][ar] = a1.x; As[ak + 5][ar] = a1.y;
            As[ak + 6][ar] = a1.z; As[ak + 7][ar] = a1.w;
        }
        {
            const float4 w0 = *(const float4*)(W + (size_t)(k0 + bk) * 128 + bc * 8);
            const float4 w1 = *(const float4*)(W + (size_t)(k0 + bk) * 128 + bc * 8 + 4);
            *(float4*)&Bs[bk][bc * 12]     = w0;
            *(float4*)&Bs[bk][bc * 12 + 4] = w1;
        }
        __syncthreads();
#pragma unroll
        for (int kk = 0; kk < 16; ++kk) {
            float a[8], b[8];
            *(float4*)&a[0] = *(const float4*)&As[kk][ty * 8];
            *(float4*)&a[4] = *(const float4*)&As[kk][ty * 8 + 4];
            *(float4*)&b[0] = *(const float4*)&Bs[kk][tx * 12];
            *(float4*)&b[4] = *(const float4*)&Bs[kk][tx * 12 + 4];
#pragma unroll
            for (int i = 0; i < 8; ++i)
#pragma unroll
                for (int j = 0; j < 8; ++j) acc[i][j] = fmaf(a[i], b[j], acc[i][j]);
        }
        __syncthreads();
    }

#pragma unroll
    for (int i = 0; i < 8; ++i) {
        const int gr = row0 + ty * 8 + i;
        if (gr >= V) continue;
#pragma unroll
        for (int j = 0; j < 8; j += 4) {
            float4 o;
            float* op = &o.x;
#pragma unroll
            for (int jj = 0; jj < 4; ++jj) {
                float x = acc[i][j + jj] + bb[tx * 8 + j + jj];
                if (lrelu) x = (x > 0.f) ? x : NEG_SLOPE * x;
                op[jj] = x;
            }
            *(float4*)(D + (size_t)gr * 128 + tx * 8 + j) = o;
        }
    }
}

// ---------------------------------------------------------------------------
// Per-target in-degree count
// ---------------------------------------------------------------------------
__global__ __launch_bounds__(256) void count_tgt(const int* __restrict__ tgt,
                                                 int* __restrict__ cnt, int E)
{
    const int e = blockIdx.x * blockDim.x + threadIdx.x;
    if (e < E) atomicAdd(cnt + tgt[e], 1);
}

// ---------------------------------------------------------------------------
// CSR build: block-wise exclusive scan of per-node counts
// ---------------------------------------------------------------------------
__global__ __launch_bounds__(256) void scan1(const int* __restrict__ cnt,
                                             int* __restrict__ offs,
                                             int* __restrict__ bsums, int V)
{
    __shared__ int sh[256];
    const int t = threadIdx.x;
    const int base = blockIdx.x * 1024;
    int v[4];
    int s = 0;
#pragma unroll
    for (int i = 0; i < 4; ++i) {
        const int idx = base + t * 4 + i;
        v[i] = (idx < V) ? cnt[idx] : 0;
        s += v[i];
    }
    sh[t] = s;
    __syncthreads();
    for (int off = 1; off < 256; off <<= 1) {
        const int x = (t >= off) ? sh[t - off] : 0;
        __syncthreads();
        sh[t] += x;
        __syncthreads();
    }
    int run = (t > 0) ? sh[t - 1] : 0;
#pragma unroll
    for (int i = 0; i < 4; ++i) {
        const int idx = base + t * 4 + i;
        if (idx < V) offs[idx] = run;
        run += v[i];
    }
    if (t == 255) bsums[blockIdx.x] = sh[255];
}

__global__ void scan2(int* __restrict__ bsums, int nb)
{
    if (threadIdx.x == 0 && blockIdx.x == 0) {
        int run = 0;
        for (int i = 0; i < nb; ++i) { const int x = bsums[i]; bsums[i] = run; run += x; }
    }
}

__global__ __launch_bounds__(256) void scan3(int* __restrict__ offs,
                                             const int* __restrict__ bsums,
                                             int* __restrict__ fill, int V)
{
    const int v = blockIdx.x * blockDim.x + threadIdx.x;
    if (v >= V) return;
    const int o = offs[v] + bsums[v >> 10];
    offs[v] = o;
    fill[v] = o;
}

// ---------------------------------------------------------------------------
// Scatter edges into target-sorted order: packed (src, edge weight) int2.
// ---------------------------------------------------------------------------
__global__ __launch_bounds__(256) void scatter_edges(
    const int* __restrict__ src, const int* __restrict__ tgt,
    const float* __restrict__ ew, int* __restrict__ fill,
    int2* __restrict__ se, int E)
{
    const int e = blockIdx.x * blockDim.x + threadIdx.x;
    if (e >= E) return;
    const int pos = atomicAdd(fill + tgt[e], 1);
    se[pos] = make_int2(src[e], __float_as_int(ew[e]));
}

// ---------------------------------------------------------------------------
// Fused per-node kernel (all f32): QK^T + exp + denom + weighted Vv
// aggregation + normalization. TWO nodes per wave (ILP): the two nodes'
// se loads / Q gathers / dots / Vv gathers are independent, halving the
// serial-latency-window count per node (R9 diagnosis: nothing saturated ->
// latency-window-bound). Static mapping (R8: grid-stride lost locality;
// R6: atomic scheduler serializes). Ksh padded [..][36]: conflict-free.
// Stage-B loop split common/tail: wave-uniform bounds, no dead loads.
// ---------------------------------------------------------------------------
__global__ __launch_bounds__(256) void fused_agg(
    const float* __restrict__ Q, const float* __restrict__ K,
    const float* __restrict__ Vv, const int2* __restrict__ se,
    const int* __restrict__ offs, const int* __restrict__ fill,
    const float* __restrict__ Wei, const float* __restrict__ bei,
    float* __restrict__ accum, int V)
{
    __shared__ float Ksh[4][2][4][36];   // [wave][node][head][32 pad 36]
    const int wid  = threadIdx.x >> 6;
    const int n0   = (blockIdx.x * 4 + wid) * 2;
    if (n0 >= V) return;
    const bool has1 = (n0 + 1) < V;
    const int l  = threadIdx.x & 63;
    const int h  = l & 3;    // stage-A head (lane = jj*4 + h)
    const int hd = l >> 4;   // stage-B head (lane owns dims 2l,2l+1)
    const int jj = l >> 2;
    const float weH = Wei[h], beH = bei[h];
    const float2* __restrict__ Vv2 = (const float2*)Vv;

    // stage both K rows into padded LDS (wave-local, no barrier needed)
    {
        const int f0 = l * 2;
        const float2 ka = *(const float2*)(K + (size_t)n0 * 128 + f0);
        Ksh[wid][0][f0 >> 5][f0 & 31] = ka.x;
        Ksh[wid][0][(f0 + 1) >> 5][(f0 + 1) & 31] = ka.y;
        if (has1) {
            const float2 kb = *(const float2*)(K + (size_t)(n0 + 1) * 128 + f0);
            Ksh[wid][1][f0 >> 5][f0 & 31] = kb.x;
            Ksh[wid][1][(f0 + 1) >> 5][(f0 + 1) & 31] = kb.y;
        }
    }

    int b0 = offs[n0],  e0 = fill[n0];
    int b1 = has1 ? offs[n0 + 1] : 0;
    int e1 = has1 ? fill[n0 + 1] : 0;

    float deg0 = 0.f, deg1 = 0.f;
    float ax0 = 0.f, ay0 = 0.f, ax1 = 0.f, ay1 = 0.f;

    while (b0 < e0 || b1 < e1) {
        const int nj0 = min(16, max(0, e0 - b0));
        const int nj1 = min(16, max(0, e1 - b1));

        int   s0 = 0, s1 = 0;
        float w0 = 0.f, w1 = 0.f, p0 = 0.f, p1 = 0.f;
        if (jj < nj0) {
            const int2 t = se[b0 + jj];
            s0 = t.x; w0 = __int_as_float(t.y);
        }
        if (jj < nj1) {
            const int2 t = se[b1 + jj];
            s1 = t.x; w1 = __int_as_float(t.y);
        }
        if (jj < nj0) {
            const float4* qp = (const float4*)(Q + (size_t)s0 * 128 + h * 32);
            float dot = 0.f;
#pragma unroll
            for (int i = 0; i < 8; ++i) {
                const float4 q = qp[i];
                const float4 k = *(const float4*)&Ksh[wid][0][h][i * 4];
                dot += q.x * k.x + q.y * k.y + q.z * k.z + q.w * k.w;
            }
            float bb = fmaf(w0, weH, beH);
            bb = (bb > 0.f) ? bb : NEG_SLOPE * bb;
            p0 = __expf(fmaf(dot, 0.17677669529663687f, bb));
        }
        if (jj < nj1) {
            const float4* qp = (const float4*)(Q + (size_t)s1 * 128 + h * 32);
            float dot = 0.f;
#pragma unroll
            for (int i = 0; i < 8; ++i) {
                const float4 q = qp[i];
                const float4 k = *(const float4*)&Ksh[wid][1][h][i * 4];
                dot += q.x * k.x + q.y * k.y + q.z * k.z + q.w * k.w;
            }
            float bb = fmaf(w1, weH, beH);
            bb = (bb > 0.f) ? bb : NEG_SLOPE * bb;
            p1 = __expf(fmaf(dot, 0.17677669529663687f, bb));
        }
        deg0 += p0;
        deg1 += p1;
        const float c0 = p0 * w0;
        const float c1 = p1 * w1;

        const int njc = min(nj0, nj1);
        int j = 0;
        for (; j < njc; ++j) {
            const float cj0 = __shfl(c0, j * 4 + hd);
            const int   sj0 = __shfl(s0, j * 4);
            const float cj1 = __shfl(c1, j * 4 + hd);
            const int   sj1 = __shfl(s1, j * 4);
            const float2 v0 = Vv2[(size_t)sj0 * 64 + l];
            const float2 v1 = Vv2[(size_t)sj1 * 64 + l];
            ax0 = fmaf(cj0, v0.x, ax0); ay0 = fmaf(cj0, v0.y, ay0);
            ax1 = fmaf(cj1, v1.x, ax1); ay1 = fmaf(cj1, v1.y, ay1);
        }
        for (; j < nj0; ++j) {
            const float cj0 = __shfl(c0, j * 4 + hd);
            const int   sj0 = __shfl(s0, j * 4);
            const float2 v0 = Vv2[(size_t)sj0 * 64 + l];
            ax0 = fmaf(cj0, v0.x, ax0); ay0 = fmaf(cj0, v0.y, ay0);
        }
        for (; j < nj1; ++j) {
            const float cj1 = __shfl(c1, j * 4 + hd);
            const int   sj1 = __shfl(s1, j * 4);
            const float2 v1 = Vv2[(size_t)sj1 * 64 + l];
            ax1 = fmaf(cj1, v1.x, ax1); ay1 = fmaf(cj1, v1.y, ay1);
        }

        b0 += nj0;
        b1 += nj1;
    }

    // reduce deg across the 16 lanes sharing head (l&3), both nodes
    float d0 = deg0, d1 = deg1;
    d0 += __shfl_xor(d0, 4);  d1 += __shfl_xor(d1, 4);
    d0 += __shfl_xor(d0, 8);  d1 += __shfl_xor(d1, 8);
    d0 += __shfl_xor(d0, 16); d1 += __shfl_xor(d1, 16);
    d0 += __shfl_xor(d0, 32); d1 += __shfl_xor(d1, 32);
    const float inv0 = 1.0f / (__shfl(d0, hd) + 1e-16f);
    const float inv1 = 1.0f / (__shfl(d1, hd) + 1e-16f);

    *(float2*)(accum + (size_t)n0 * 128 + l * 2) =
        make_float2(ax0 * inv0, ay0 * inv0);
    if (has1)
        *(float2*)(accum + (size_t)(n0 + 1) * 128 + l * 2) =
            make_float2(ax1 * inv1, ay1 * inv1);
}

// ---------------------------------------------------------------------------
extern "C" void kernel_launch(void* const* d_in, const int* in_sizes, int n_in,
                              void* d_out, int out_size, void* d_ws, size_t ws_size,
                              hipStream_t stream)
{
    const float* h   = (const float*)d_in[0];
    const int*   ei  = (const int*)  d_in[1];
    const float* ew  = (const float*)d_in[2];
    const float* Wq  = (const float*)d_in[3];
    const float* bq  = (const float*)d_in[4];
    const float* Wk  = (const float*)d_in[5];
    const float* bk  = (const float*)d_in[6];
    const float* Wv  = (const float*)d_in[7];
    const float* bv  = (const float*)d_in[8];
    const float* Wo  = (const float*)d_in[9];
    const float* bo  = (const float*)d_in[10];
    const float* Wei = (const float*)d_in[11];
    const float* bei = (const float*)d_in[12];

    const int V = in_sizes[0] / 128;
    const int E = in_sizes[2];
    const int* src = ei;
    const int* tgt = ei + E;

    // workspace layout
    float* Q     = (float*)d_ws;
    float* Km    = Q  + (size_t)V * 128;
    float* Vm    = Km + (size_t)V * 128;
    float* accum = Vm + (size_t)V * 128;
    int2*  se    = (int2*)(accum + (size_t)V * 128);
    int*   cnt   = (int*)(se + E);
    int*   offs  = cnt  + V;
    int*   fill  = offs + V + 1;
    int*   bsums = fill + V;

    hipMemsetAsync(cnt, 0, (size_t)V * sizeof(int), stream);

    const int bigGrid = (V + 127) / 128;
    gemm_big<<<dim3(bigGrid, 3), 256, 0, stream>>>(
        h, Wq, Wk, Wv, bq, bk, bv, Q, Km, Vm, V, 0);

    count_tgt<<<(E + 255) / 256, 256, 0, stream>>>(tgt, cnt, E);
    const int nb = (V + 1023) / 1024;
    scan1<<<nb, 256, 0, stream>>>(cnt, offs, bsums, V);
    scan2<<<1, 64, 0, stream>>>(bsums, nb);
    scan3<<<(V + 255) / 256, 256, 0, stream>>>(offs, bsums, fill, V);
    scatter_edges<<<(E + 255) / 256, 256, 0, stream>>>(
        src, tgt, ew, fill, se, E);

    // 2 nodes per wave, 8 per block
    fused_agg<<<(V + 7) / 8, 256, 0, stream>>>(
        Q, Km, Vm, se, offs, fill, Wei, bei, accum, V);

    gemm_big<<<dim3(bigGrid, 1), 256, 0, stream>>>(
        accum, Wo, Wo, Wo, bo, bo, bo, (float*)d_out, (float*)d_out, (float*)d_out, V, 1);
}